// Round 6
// baseline (188.499 us; speedup 1.0000x reference)
//
#include <hip/hip_runtime.h>
#include <stdint.h>

#define Bdim 4
#define Ldim 512
#define Hdim 768
#define Edim 10
#define Rdim 10

typedef __attribute__((ext_vector_type(8))) short short8;
typedef __attribute__((ext_vector_type(4))) float floatx4;

__device__ __forceinline__ unsigned short f2bf(float x) {
    unsigned int u = __float_as_uint(x);
    unsigned int r = (u + 0x7fffu + ((u >> 16) & 1u)) >> 16;
    return (unsigned short)r;
}
__device__ __forceinline__ float bf2f(unsigned short u) {
    return __uint_as_float(((unsigned int)u) << 16);
}

#define GLOAD_LDS16(g, l)                                                      \
    __builtin_amdgcn_global_load_lds(                                          \
        (const __attribute__((address_space(1))) void*)(g),                    \
        (__attribute__((address_space(3))) void*)(l), 16, 0, 0)

#define WAITVM(n) asm volatile("s_waitcnt vmcnt(" #n ")" ::: "memory")

// ---------------- fused f32 -> bf16 conversion (4 segments) ----------------
__global__ void k_cvt4(const float* __restrict__ s0, unsigned short* __restrict__ d0, int n0,
                       const float* __restrict__ s1, unsigned short* __restrict__ d1, int n1,
                       const float* __restrict__ s2, unsigned short* __restrict__ d2, int n2,
                       const float* __restrict__ s3, unsigned short* __restrict__ d3, int n3) {
    int total = n0 + n1 + n2 + n3;   // in float4 units
    int i = blockIdx.x * blockDim.x + threadIdx.x;
    int stride = gridDim.x * blockDim.x;
    for (; i < total; i += stride) {
        const float* s; unsigned short* d; int j = i;
        if (j < n0) { s = s0; d = d0; }
        else { j -= n0;
            if (j < n1) { s = s1; d = d1; }
            else { j -= n1;
                if (j < n2) { s = s2; d = d2; }
                else { j -= n2; s = s3; d = d3; }
            }
        }
        float4 v = reinterpret_cast<const float4*>(s)[j];
        ushort4 o;
        o.x = f2bf(v.x); o.y = f2bf(v.y); o.z = f2bf(v.z); o.w = f2bf(v.w);
        reinterpret_cast<ushort4*>(d)[j] = o;
    }
}

// bijective XCD remap of a linear block id (all our grids are %8==0)
__device__ __forceinline__ int xcd_swz(int bid, int nwg) {
    int cpx = nwg >> 3;
    return (bid & 7) * cpx + (bid >> 3);
}

// ===================== 128^2 dbuf core (kept for k_gemm_proj) ===============
__device__ __forceinline__ void gemm_bt_core64_db(
    const unsigned short* __restrict__ A, int lda,
    const unsigned short* __restrict__ Bm, int ldb,
    int K,
    unsigned short* lA, unsigned short* lB,
    floatx4 acc[4][4])
{
    const int tid  = threadIdx.x;
    const int lane = tid & 63;
    const int wave = tid >> 6;
    const int wr = wave >> 1;
    const int wc = wave & 1;

    const int srow   = tid >> 3;
    const int schunk = (tid & 7) ^ (srow & 7);
    const int skk    = schunk << 3;

    const int frow = lane & 15;
    const int fs   = lane >> 4;

    #pragma unroll
    for (int i = 0; i < 4; ++i) {
        GLOAD_LDS16(A  + (size_t)(srow + 32 * i) * lda + skk,
                    lA + (tid + 256 * i) * 8);
        GLOAD_LDS16(Bm + (size_t)(srow + 32 * i) * ldb + skk,
                    lB + (tid + 256 * i) * 8);
    }
    __syncthreads();

    const int nt = K >> 6;
    int buf = 0;
    for (int kt = 0; kt < nt; ++kt) {
        if (kt + 1 < nt) {
            const int k0n = (kt + 1) << 6;
            unsigned short* dA = lA + (buf ^ 1) * 8192;
            unsigned short* dB = lB + (buf ^ 1) * 8192;
            #pragma unroll
            for (int i = 0; i < 4; ++i) {
                GLOAD_LDS16(A  + (size_t)(srow + 32 * i) * lda + k0n + skk,
                            dA + (tid + 256 * i) * 8);
                GLOAD_LDS16(Bm + (size_t)(srow + 32 * i) * ldb + k0n + skk,
                            dB + (tid + 256 * i) * 8);
            }
        }
        const unsigned short* sA = lA + buf * 8192;
        const unsigned short* sB = lB + buf * 8192;
        #pragma unroll
        for (int h = 0; h < 2; ++h) {
            short8 af[4], bfr[4];
            #pragma unroll
            for (int mi = 0; mi < 4; ++mi) {
                int row  = wr * 64 + mi * 16 + frow;
                int slot = (fs + 4 * h) ^ (row & 7);
                af[mi] = *reinterpret_cast<const short8*>(sA + row * 64 + slot * 8);
            }
            #pragma unroll
            for (int ni = 0; ni < 4; ++ni) {
                int row  = wc * 64 + ni * 16 + frow;
                int slot = (fs + 4 * h) ^ (row & 7);
                bfr[ni] = *reinterpret_cast<const short8*>(sB + row * 64 + slot * 8);
            }
            #pragma unroll
            for (int mi = 0; mi < 4; ++mi)
                #pragma unroll
                for (int ni = 0; ni < 4; ++ni)
                    acc[mi][ni] = __builtin_amdgcn_mfma_f32_16x16x32_bf16(
                        af[mi], bfr[ni], acc[mi][ni], 0, 0, 0);
        }
        __syncthreads();
        buf ^= 1;
    }
}

// ====== 256^2 core, BK=32, 4-slot pipeline, counted vmcnt (T4) ==============
// K fixed = 768 -> NT = 24 tiles of 32.
// LDS per matrix: 4 slots x [256 rows][4 chunks of 8 bf16] = 4*16KB = 64KB.
// Slot rotation: tile k lives in slot k&3. Iteration k:
//   vmcnt(8)   : tiles <= k landed (k+1, k+2 still in flight - never drain)
//   s_barrier  : all waves' tile-k loads landed; all reads of tile k-1 done
//   stage k+3  : into slot (k+3)&3 (disjoint from k being read, k+1, k+2)
//   compute k  : 12 ds_read_b128 + 32 MFMA per wave from slot k&3
// Race-free by construction: a slot is overwritten only 4 tiles after its
// last read, behind a barrier. Bank swizzle: chunk c of row r stored at
// physical slot c ^ ((r ^ (r>>2)) & 3)  (pre-swizzled global source, linear
// LDS dest for global_load_lds, same XOR on ds_read - rule #21).
__device__ __forceinline__ void gemm_bt_core256_p4(
    const unsigned short* __restrict__ A, int lda,
    const unsigned short* __restrict__ Bm, int ldb,
    unsigned short* lA, unsigned short* lB,
    floatx4 acc[8][4])
{
    const int tid  = threadIdx.x;       // 0..511
    const int lane = tid & 63;
    const int wave = tid >> 6;          // 0..7
    const int wr = wave >> 2;           // 0..1  (M)
    const int wc = wave & 3;            // 0..3  (N)

    // ---- staging geometry: unit u covers (row=u>>2, physical chunk=u&3) ----
    const int srow0 = tid >> 2;                    // 0..127 (unit tid)
    const int pchk  = tid & 3;
    const int swz0  = ((srow0 ^ (srow0 >> 2)) & 3);  // same for row srow0+128
    const int lchk  = pchk ^ swz0;                 // logical k-chunk
    // running global pointers (advance by 32 per staged tile)
    const unsigned short* pA0 = A  + (size_t)srow0 * lda + lchk * 8;
    const unsigned short* pA1 = A  + (size_t)(srow0 + 128) * lda + lchk * 8;
    const unsigned short* pB0 = Bm + (size_t)srow0 * ldb + lchk * 8;
    const unsigned short* pB1 = Bm + (size_t)(srow0 + 128) * ldb + lchk * 8;

    // ---- fragment-read offsets (ushort units), precomputed ----
    const int frow = lane & 15;
    const int fs   = lane >> 4;                    // 0..3 = k-chunk
    int offA[8], offB[4];
    #pragma unroll
    for (int mi = 0; mi < 8; ++mi) {
        int row  = wr * 128 + mi * 16 + frow;
        int slot = fs ^ ((row ^ (row >> 2)) & 3);
        offA[mi] = row * 32 + slot * 8;
    }
    #pragma unroll
    for (int ni = 0; ni < 4; ++ni) {
        int row  = wc * 64 + ni * 16 + frow;
        int slot = fs ^ ((row ^ (row >> 2)) & 3);
        offB[ni] = row * 32 + slot * 8;
    }

    #define STAGE_P4(s)                                                        \
        do {                                                                   \
            GLOAD_LDS16(pA0, lA + (s) * 8192 + tid * 8);                       \
            GLOAD_LDS16(pA1, lA + (s) * 8192 + (tid + 512) * 8);               \
            GLOAD_LDS16(pB0, lB + (s) * 8192 + tid * 8);                       \
            GLOAD_LDS16(pB1, lB + (s) * 8192 + (tid + 512) * 8);               \
            pA0 += 32; pA1 += 32; pB0 += 32; pB1 += 32;                        \
        } while (0)

    #define COMPUTE_P4(s)                                                      \
        do {                                                                   \
            const unsigned short* sA = lA + (s) * 8192;                        \
            const unsigned short* sB = lB + (s) * 8192;                        \
            short8 af[8], bfr[4];                                              \
            _Pragma("unroll")                                                  \
            for (int ni = 0; ni < 4; ++ni)                                     \
                bfr[ni] = *reinterpret_cast<const short8*>(sB + offB[ni]);     \
            _Pragma("unroll")                                                  \
            for (int mi = 0; mi < 8; ++mi)                                     \
                af[mi] = *reinterpret_cast<const short8*>(sA + offA[mi]);      \
            _Pragma("unroll")                                                  \
            for (int mi = 0; mi < 8; ++mi)                                     \
                _Pragma("unroll")                                              \
                for (int ni = 0; ni < 4; ++ni)                                 \
                    acc[mi][ni] = __builtin_amdgcn_mfma_f32_16x16x32_bf16(     \
                        af[mi], bfr[ni], acc[mi][ni], 0, 0, 0);                \
        } while (0)

    // prologue: stage tiles 0,1,2 (12 loads outstanding per wave)
    STAGE_P4(0);
    STAGE_P4(1);
    STAGE_P4(2);

    // main loop: tiles 0..21 (NT=24)
    for (int k = 0; k < 22; ++k) {
        WAITVM(8);                         // tile k landed (k+1,k+2 flying)
        __builtin_amdgcn_s_barrier();
        if (k < 21) {
            const int s = (k + 3) & 3;
            STAGE_P4(s);
        }
        COMPUTE_P4(k & 3);
    }
    // tail: tile 22 (only t23 in flight), tile 23 (drain)
    WAITVM(4);
    __builtin_amdgcn_s_barrier();
    COMPUTE_P4(22 & 3);
    WAITVM(0);
    __builtin_amdgcn_s_barrier();
    COMPUTE_P4(23 & 3);

    #undef STAGE_P4
    #undef COMPUTE_P4
}

// ---------------- GEMM1: hp = relu(h @ Wproj^T + b) -> bf16 (128^2) --------
__global__ __launch_bounds__(256) void k_gemm_proj(
    const unsigned short* __restrict__ hA,
    const unsigned short* __restrict__ Wp,
    const float* __restrict__ bproj,
    unsigned short* __restrict__ hp)
{
    __shared__ unsigned short lA[2 * 128 * 64];
    __shared__ unsigned short lB[2 * 128 * 64];
    int bid = xcd_swz(blockIdx.x + gridDim.x * blockIdx.y, gridDim.x * gridDim.y);
    const int m0 = (bid % gridDim.x) * 128;
    const int n0 = (bid / gridDim.x) * 128;
    floatx4 acc[4][4];
    #pragma unroll
    for (int i = 0; i < 4; ++i)
        #pragma unroll
        for (int j = 0; j < 4; ++j)
            acc[i][j] = (floatx4){0.f, 0.f, 0.f, 0.f};

    gemm_bt_core64_db(hA + (size_t)m0 * Hdim, Hdim,
                      Wp + (size_t)n0 * Hdim, Hdim, Hdim, lA, lB, acc);

    const int tid = threadIdx.x, lane = tid & 63, wave = tid >> 6;
    const int wr = wave >> 1, wc = wave & 1;
    const int cl = lane & 15, rh = (lane >> 4) * 4;
    #pragma unroll
    for (int mi = 0; mi < 4; ++mi)
        #pragma unroll
        for (int ni = 0; ni < 4; ++ni)
            #pragma unroll
            for (int j = 0; j < 4; ++j) {
                int r = m0 + wr * 64 + mi * 16 + rh + j;
                int c = n0 + wc * 64 + ni * 16 + cl;
                float v = acc[mi][ni][j] + bproj[c];
                hp[(size_t)r * Hdim + c] = f2bf(fmaxf(v, 0.0f));
            }
}

// -------- GEMM2 (256^2 p4): T[m, r*768+h] = hp @ Wbil^T -> bf16 ------------
__global__ __launch_bounds__(512, 1) void k_gemm_t(
    const unsigned short* __restrict__ hp,
    const unsigned short* __restrict__ Wb,
    unsigned short* __restrict__ T)
{
    __shared__ unsigned short lA[4 * 256 * 32];
    __shared__ unsigned short lB[4 * 256 * 32];
    int bid = xcd_swz(blockIdx.x + gridDim.x * blockIdx.y, gridDim.x * gridDim.y);
    const int m0 = (bid % gridDim.x) * 256;
    const int n0 = (bid / gridDim.x) * 256;   // over R*H = 7680
    floatx4 acc[8][4];
    #pragma unroll
    for (int i = 0; i < 8; ++i)
        #pragma unroll
        for (int j = 0; j < 4; ++j)
            acc[i][j] = (floatx4){0.f, 0.f, 0.f, 0.f};

    gemm_bt_core256_p4(hp + (size_t)m0 * Hdim, Hdim,
                       Wb + (size_t)n0 * Hdim, Hdim, lA, lB, acc);

    const int tid = threadIdx.x, lane = tid & 63, wave = tid >> 6;
    const int wr = wave >> 2, wc = wave & 3;
    const int cl = lane & 15, rh = (lane >> 4) * 4;
    #pragma unroll
    for (int mi = 0; mi < 8; ++mi)
        #pragma unroll
        for (int ni = 0; ni < 4; ++ni)
            #pragma unroll
            for (int j = 0; j < 4; ++j) {
                int r = m0 + wr * 128 + mi * 16 + rh + j;
                int c = n0 + wc * 64 + ni * 16 + cl;
                T[(size_t)r * (Rdim * Hdim) + c] = f2bf(acc[mi][ni][j]);
            }
}

// ------ GEMM3 (256^2 p4, N-merged): rel[grow, m*10+r] = hp @ T2_b^T + b ----
__global__ __launch_bounds__(512, 1) void k_gemm_rel(
    const unsigned short* __restrict__ hp,
    const unsigned short* __restrict__ T,
    const float* __restrict__ bbil,
    float* __restrict__ rel)
{
    __shared__ unsigned short lA[4 * 256 * 32];
    __shared__ unsigned short lB[4 * 256 * 32];
    int bid = xcd_swz(blockIdx.x + gridDim.x * blockIdx.y, gridDim.x * gridDim.y);
    const int m0 = (bid % gridDim.x) * 256;   // global row over 2048
    const int n0 = (bid / gridDim.x) * 256;   // merged (m,r) over 5120
    const int b  = m0 >> 9;
    floatx4 acc[8][4];
    #pragma unroll
    for (int i = 0; i < 8; ++i)
        #pragma unroll
        for (int j = 0; j < 4; ++j)
            acc[i][j] = (floatx4){0.f, 0.f, 0.f, 0.f};

    const unsigned short* Ab = hp + (size_t)m0 * Hdim;
    const unsigned short* Bb = T + (size_t)b * Ldim * (Rdim * Hdim) + (size_t)n0 * Hdim;
    gemm_bt_core256_p4(Ab, Hdim, Bb, Hdim, lA, lB, acc);

    const int tid = threadIdx.x, lane = tid & 63, wave = tid >> 6;
    const int wr = wave >> 2, wc = wave & 3;
    const int cl = lane & 15, rh = (lane >> 4) * 4;
    #pragma unroll
    for (int mi = 0; mi < 8; ++mi)
        #pragma unroll
        for (int ni = 0; ni < 4; ++ni) {
            int n = n0 + wc * 64 + ni * 16 + cl;
            float bias = bbil[n % Rdim];
            #pragma unroll
            for (int j = 0; j < 4; ++j) {
                int grow = m0 + wr * 128 + mi * 16 + rh + j;
                rel[(size_t)grow * (Ldim * Rdim) + n] = acc[mi][ni][j] + bias;
            }
        }
}

// ---------------- ent_logits: wave-per-row, 10 dots of length 768 ----------
__global__ __launch_bounds__(256) void k_ent(
    const unsigned short* __restrict__ hp,
    const unsigned short* __restrict__ We,
    const float* __restrict__ bent,
    float* __restrict__ out)
{
    const int gw = (blockIdx.x * blockDim.x + threadIdx.x) >> 6;  // wave id
    const int lane = threadIdx.x & 63;
    if (gw >= Bdim * Ldim) return;
    const unsigned short* row = hp + (size_t)gw * Hdim;
    float hv[12];
    #pragma unroll
    for (int j = 0; j < 12; ++j) hv[j] = bf2f(row[lane + j * 64]);
    #pragma unroll
    for (int e = 0; e < Edim; ++e) {
        const unsigned short* wrow = We + e * Hdim;
        float s = 0.f;
        #pragma unroll
        for (int j = 0; j < 12; ++j) s += hv[j] * bf2f(wrow[lane + j * 64]);
        #pragma unroll
        for (int off = 32; off >= 1; off >>= 1) s += __shfl_xor(s, off);
        if (lane == 0) out[(size_t)gw * Edim + e] = s + bent[e];
    }
}

extern "C" void kernel_launch(void* const* d_in, const int* in_sizes, int n_in,
                              void* d_out, int out_size, void* d_ws, size_t ws_size,
                              hipStream_t stream)
{
    const float* h     = (const float*)d_in[0];
    const float* Wproj = (const float*)d_in[1];
    const float* bproj = (const float*)d_in[2];
    const float* Went  = (const float*)d_in[3];
    const float* bent  = (const float*)d_in[4];
    const float* Wbil  = (const float*)d_in[5];
    const float* bbil  = (const float*)d_in[6];

    float* out_ent = (float*)d_out;
    float* out_rel = (float*)d_out + (size_t)Bdim * Ldim * Edim;

    unsigned short* h_bf  = (unsigned short*)d_ws;
    unsigned short* Wp_bf = h_bf  + (size_t)2048 * Hdim;
    unsigned short* Wb_bf = Wp_bf + (size_t)Hdim * Hdim;
    unsigned short* We_bf = Wb_bf + (size_t)Rdim * Hdim * Hdim;
    unsigned short* hp_bf = We_bf + (size_t)Edim * Hdim;
    unsigned short* T_bf  = hp_bf + (size_t)2048 * Hdim;   // 2048 x 7680

    // single fused conversion launch
    {
        int n0 = 2048 * Hdim / 4;
        int n1 = Hdim * Hdim / 4;
        int n2 = Rdim * Hdim * Hdim / 4;
        int n3 = Edim * Hdim / 4;
        k_cvt4<<<dim3(2048), 256, 0, stream>>>(h, h_bf, n0, Wproj, Wp_bf, n1,
                                               Wbil, Wb_bf, n2, Went, We_bf, n3);
    }

    // GEMM1: hp = relu(h @ Wproj^T + b)   (2048x768) * (768x768), 128^2 tiles
    k_gemm_proj<<<dim3(2048 / 128, Hdim / 128), 256, 0, stream>>>(h_bf, Wp_bf, bproj, hp_bf);

    // ent logits (needs hp)
    k_ent<<<dim3((Bdim * Ldim * 64) / 256), 256, 0, stream>>>(hp_bf, We_bf, bent, out_ent);

    // GEMM2: T = hp @ Wbil^T   (2048x768)*(768x7680), 256^2 tiles, 240 blocks
    k_gemm_t<<<dim3(2048 / 256, (Rdim * Hdim) / 256), 512, 0, stream>>>(hp_bf, Wb_bf, T_bf);

    // GEMM3: rel  (2048 x 5120 x 768, per-256-row-tile B), 160 blocks
    k_gemm_rel<<<dim3(2048 / 256, (Ldim * Rdim) / 256), 512, 0, stream>>>(hp_bf, T_bf, bbil, out_rel);
}

// Round 7
// 174.450 us; speedup vs baseline: 1.0805x; 1.0805x over previous
//
#include <hip/hip_runtime.h>
#include <stdint.h>

#define Bdim 4
#define Ldim 512
#define Hdim 768
#define Edim 10
#define Rdim 10

typedef __attribute__((ext_vector_type(8))) short short8;
typedef __attribute__((ext_vector_type(4))) float floatx4;

__device__ __forceinline__ unsigned short f2bf(float x) {
    unsigned int u = __float_as_uint(x);
    unsigned int r = (u + 0x7fffu + ((u >> 16) & 1u)) >> 16;
    return (unsigned short)r;
}
__device__ __forceinline__ float bf2f(unsigned short u) {
    return __uint_as_float(((unsigned int)u) << 16);
}

#define GLOAD_LDS16(g, l)                                                      \
    __builtin_amdgcn_global_load_lds(                                          \
        (const __attribute__((address_space(1))) void*)(g),                    \
        (__attribute__((address_space(3))) void*)(l), 16, 0, 0)

#define WAITVM(n) asm volatile("s_waitcnt vmcnt(" #n ")" ::: "memory")

// ---------------- fused f32 -> bf16 conversion (4 segments) ----------------
__global__ void k_cvt4(const float* __restrict__ s0, unsigned short* __restrict__ d0, int n0,
                       const float* __restrict__ s1, unsigned short* __restrict__ d1, int n1,
                       const float* __restrict__ s2, unsigned short* __restrict__ d2, int n2,
                       const float* __restrict__ s3, unsigned short* __restrict__ d3, int n3) {
    int total = n0 + n1 + n2 + n3;   // in float4 units
    int i = blockIdx.x * blockDim.x + threadIdx.x;
    int stride = gridDim.x * blockDim.x;
    for (; i < total; i += stride) {
        const float* s; unsigned short* d; int j = i;
        if (j < n0) { s = s0; d = d0; }
        else { j -= n0;
            if (j < n1) { s = s1; d = d1; }
            else { j -= n1;
                if (j < n2) { s = s2; d = d2; }
                else { j -= n2; s = s3; d = d3; }
            }
        }
        float4 v = reinterpret_cast<const float4*>(s)[j];
        ushort4 o;
        o.x = f2bf(v.x); o.y = f2bf(v.y); o.z = f2bf(v.z); o.w = f2bf(v.w);
        reinterpret_cast<ushort4*>(d)[j] = o;
    }
}

// bijective XCD remap of a linear block id (all our grids are %8==0)
__device__ __forceinline__ int xcd_swz(int bid, int nwg) {
    int cpx = nwg >> 3;
    return (bid & 7) * cpx + (bid >> 3);
}

// ===================== 128^2 dbuf core (kept for k_gemm_proj) ===============
__device__ __forceinline__ void gemm_bt_core64_db(
    const unsigned short* __restrict__ A, int lda,
    const unsigned short* __restrict__ Bm, int ldb,
    int K,
    unsigned short* lA, unsigned short* lB,
    floatx4 acc[4][4])
{
    const int tid  = threadIdx.x;
    const int lane = tid & 63;
    const int wave = tid >> 6;
    const int wr = wave >> 1;
    const int wc = wave & 1;

    const int srow   = tid >> 3;
    const int schunk = (tid & 7) ^ (srow & 7);
    const int skk    = schunk << 3;

    const int frow = lane & 15;
    const int fs   = lane >> 4;

    #pragma unroll
    for (int i = 0; i < 4; ++i) {
        GLOAD_LDS16(A  + (size_t)(srow + 32 * i) * lda + skk,
                    lA + (tid + 256 * i) * 8);
        GLOAD_LDS16(Bm + (size_t)(srow + 32 * i) * ldb + skk,
                    lB + (tid + 256 * i) * 8);
    }
    __syncthreads();

    const int nt = K >> 6;
    int buf = 0;
    for (int kt = 0; kt < nt; ++kt) {
        if (kt + 1 < nt) {
            const int k0n = (kt + 1) << 6;
            unsigned short* dA = lA + (buf ^ 1) * 8192;
            unsigned short* dB = lB + (buf ^ 1) * 8192;
            #pragma unroll
            for (int i = 0; i < 4; ++i) {
                GLOAD_LDS16(A  + (size_t)(srow + 32 * i) * lda + k0n + skk,
                            dA + (tid + 256 * i) * 8);
                GLOAD_LDS16(Bm + (size_t)(srow + 32 * i) * ldb + k0n + skk,
                            dB + (tid + 256 * i) * 8);
            }
        }
        const unsigned short* sA = lA + buf * 8192;
        const unsigned short* sB = lB + buf * 8192;
        #pragma unroll
        for (int h = 0; h < 2; ++h) {
            short8 af[4], bfr[4];
            #pragma unroll
            for (int mi = 0; mi < 4; ++mi) {
                int row  = wr * 64 + mi * 16 + frow;
                int slot = (fs + 4 * h) ^ (row & 7);
                af[mi] = *reinterpret_cast<const short8*>(sA + row * 64 + slot * 8);
            }
            #pragma unroll
            for (int ni = 0; ni < 4; ++ni) {
                int row  = wc * 64 + ni * 16 + frow;
                int slot = (fs + 4 * h) ^ (row & 7);
                bfr[ni] = *reinterpret_cast<const short8*>(sB + row * 64 + slot * 8);
            }
            #pragma unroll
            for (int mi = 0; mi < 4; ++mi)
                #pragma unroll
                for (int ni = 0; ni < 4; ++ni)
                    acc[mi][ni] = __builtin_amdgcn_mfma_f32_16x16x32_bf16(
                        af[mi], bfr[ni], acc[mi][ni], 0, 0, 0);
        }
        __syncthreads();
        buf ^= 1;
    }
}

// ====== 256^2 core, BK=64, dbuf, counted vmcnt (no drain in main loop) ======
// R5 geometry (proven layout + 3-bit XOR swizzle, ~0 bank conflicts), new sync:
//   per K-tile kt:
//     s_barrier            all waves' reads of tile kt-1 have returned
//     STAGE(kt+1)->buf^1   overwrites tile kt-1 (safe); 8 loads fly under MFMA
//     vmcnt(8)             tile kt's 8 loads retired (in-order); kt+1 in flight
//     s_barrier            tile kt globally visible in LDS
//     COMPUTE(kt)          24 ds_read_b128 + 64 MFMA, no vmcnt(0) anywhere
__device__ __forceinline__ void gemm_bt_core256_cnt(
    const unsigned short* __restrict__ A, int lda,
    const unsigned short* __restrict__ Bm, int ldb,
    unsigned short* lA, unsigned short* lB,
    floatx4 acc[8][4])
{
    const int tid  = threadIdx.x;       // 0..511
    const int lane = tid & 63;
    const int wave = tid >> 6;          // 0..7
    const int wr = wave >> 2;           // 0..1  (M)
    const int wc = wave & 3;            // 0..3  (N)

    // staging: 512 threads x 16B chunk; 8 chunks/row -> 64 rows per instr
    const int srow   = tid >> 3;                  // 0..63
    const int schunk = (tid & 7) ^ (srow & 7);    // pre-swizzled k-chunk
    const int skk    = schunk << 3;

    const int frow = lane & 15;
    const int fs   = lane >> 4;                   // 0..3

    #define STAGE256(t, buf)                                                   \
        do {                                                                   \
            const int k0s = (t) << 6;                                          \
            unsigned short* dA = lA + (buf) * 16384;                           \
            unsigned short* dB = lB + (buf) * 16384;                           \
            _Pragma("unroll")                                                  \
            for (int i = 0; i < 4; ++i) {                                      \
                GLOAD_LDS16(A  + (size_t)(srow + 64 * i) * lda + k0s + skk,    \
                            dA + (tid + 512 * i) * 8);                         \
                GLOAD_LDS16(Bm + (size_t)(srow + 64 * i) * ldb + k0s + skk,    \
                            dB + (tid + 512 * i) * 8);                         \
            }                                                                  \
        } while (0)

    #define COMPUTE256(buf)                                                    \
        do {                                                                   \
            const unsigned short* sA = lA + (buf) * 16384;                     \
            const unsigned short* sB = lB + (buf) * 16384;                     \
            _Pragma("unroll")                                                  \
            for (int h = 0; h < 2; ++h) {                                      \
                short8 bfr[4];                                                 \
                _Pragma("unroll")                                              \
                for (int ni = 0; ni < 4; ++ni) {                               \
                    int row  = wc * 64 + ni * 16 + frow;                       \
                    int slot = (fs + 4 * h) ^ (row & 7);                       \
                    bfr[ni] = *reinterpret_cast<const short8*>(                \
                        sB + row * 64 + slot * 8);                             \
                }                                                              \
                _Pragma("unroll")                                              \
                for (int mi = 0; mi < 8; ++mi) {                               \
                    int row  = wr * 128 + mi * 16 + frow;                      \
                    int slot = (fs + 4 * h) ^ (row & 7);                       \
                    short8 af = *reinterpret_cast<const short8*>(              \
                        sA + row * 64 + slot * 8);                             \
                    _Pragma("unroll")                                          \
                    for (int ni = 0; ni < 4; ++ni)                             \
                        acc[mi][ni] = __builtin_amdgcn_mfma_f32_16x16x32_bf16( \
                            af, bfr[ni], acc[mi][ni], 0, 0, 0);                \
                }                                                              \
            }                                                                  \
        } while (0)

    const int NT = Hdim >> 6;   // 12

    STAGE256(0, 0);
    for (int kt = 0; kt < NT - 1; ++kt) {
        __builtin_amdgcn_s_barrier();          // readers of tile kt-1 done
        STAGE256(kt + 1, (kt + 1) & 1);        // overwrite tile kt-1's buffer
        WAITVM(8);                             // tile kt landed; kt+1 in flight
        __builtin_amdgcn_s_barrier();          // all waves have tile kt
        __builtin_amdgcn_sched_barrier(0);     // keep ds_reads below barrier
        COMPUTE256(kt & 1);
    }
    __builtin_amdgcn_s_barrier();
    WAITVM(0);                                 // final tile: drain is fine
    __builtin_amdgcn_s_barrier();
    __builtin_amdgcn_sched_barrier(0);
    COMPUTE256((NT - 1) & 1);

    #undef STAGE256
    #undef COMPUTE256
}

// ---------------- GEMM1: hp = relu(h @ Wproj^T + b) -> bf16 (128^2) --------
__global__ __launch_bounds__(256) void k_gemm_proj(
    const unsigned short* __restrict__ hA,
    const unsigned short* __restrict__ Wp,
    const float* __restrict__ bproj,
    unsigned short* __restrict__ hp)
{
    __shared__ unsigned short lA[2 * 128 * 64];
    __shared__ unsigned short lB[2 * 128 * 64];
    int bid = xcd_swz(blockIdx.x + gridDim.x * blockIdx.y, gridDim.x * gridDim.y);
    const int m0 = (bid % gridDim.x) * 128;
    const int n0 = (bid / gridDim.x) * 128;
    floatx4 acc[4][4];
    #pragma unroll
    for (int i = 0; i < 4; ++i)
        #pragma unroll
        for (int j = 0; j < 4; ++j)
            acc[i][j] = (floatx4){0.f, 0.f, 0.f, 0.f};

    gemm_bt_core64_db(hA + (size_t)m0 * Hdim, Hdim,
                      Wp + (size_t)n0 * Hdim, Hdim, Hdim, lA, lB, acc);

    const int tid = threadIdx.x, lane = tid & 63, wave = tid >> 6;
    const int wr = wave >> 1, wc = wave & 1;
    const int cl = lane & 15, rh = (lane >> 4) * 4;
    #pragma unroll
    for (int mi = 0; mi < 4; ++mi)
        #pragma unroll
        for (int ni = 0; ni < 4; ++ni)
            #pragma unroll
            for (int j = 0; j < 4; ++j) {
                int r = m0 + wr * 64 + mi * 16 + rh + j;
                int c = n0 + wc * 64 + ni * 16 + cl;
                float v = acc[mi][ni][j] + bproj[c];
                hp[(size_t)r * Hdim + c] = f2bf(fmaxf(v, 0.0f));
            }
}

// -------- GEMM2 (256^2 cnt): T[m, r*768+h] = hp @ Wbil^T -> bf16 -----------
__global__ __launch_bounds__(512, 1) void k_gemm_t(
    const unsigned short* __restrict__ hp,
    const unsigned short* __restrict__ Wb,
    unsigned short* __restrict__ T)
{
    __shared__ unsigned short lA[2 * 256 * 64];
    __shared__ unsigned short lB[2 * 256 * 64];
    int bid = xcd_swz(blockIdx.x + gridDim.x * blockIdx.y, gridDim.x * gridDim.y);
    const int m0 = (bid % gridDim.x) * 256;
    const int n0 = (bid / gridDim.x) * 256;   // over R*H = 7680
    floatx4 acc[8][4];
    #pragma unroll
    for (int i = 0; i < 8; ++i)
        #pragma unroll
        for (int j = 0; j < 4; ++j)
            acc[i][j] = (floatx4){0.f, 0.f, 0.f, 0.f};

    gemm_bt_core256_cnt(hp + (size_t)m0 * Hdim, Hdim,
                        Wb + (size_t)n0 * Hdim, Hdim, lA, lB, acc);

    const int tid = threadIdx.x, lane = tid & 63, wave = tid >> 6;
    const int wr = wave >> 2, wc = wave & 3;
    const int cl = lane & 15, rh = (lane >> 4) * 4;
    #pragma unroll
    for (int mi = 0; mi < 8; ++mi)
        #pragma unroll
        for (int ni = 0; ni < 4; ++ni)
            #pragma unroll
            for (int j = 0; j < 4; ++j) {
                int r = m0 + wr * 128 + mi * 16 + rh + j;
                int c = n0 + wc * 64 + ni * 16 + cl;
                T[(size_t)r * (Rdim * Hdim) + c] = f2bf(acc[mi][ni][j]);
            }
}

// ------ GEMM3 (256^2 cnt, N-merged): rel[grow, m*10+r] = hp @ T2_b^T + b ---
__global__ __launch_bounds__(512, 1) void k_gemm_rel(
    const unsigned short* __restrict__ hp,
    const unsigned short* __restrict__ T,
    const float* __restrict__ bbil,
    float* __restrict__ rel)
{
    __shared__ unsigned short lA[2 * 256 * 64];
    __shared__ unsigned short lB[2 * 256 * 64];
    int bid = xcd_swz(blockIdx.x + gridDim.x * blockIdx.y, gridDim.x * gridDim.y);
    const int m0 = (bid % gridDim.x) * 256;   // global row over 2048
    const int n0 = (bid / gridDim.x) * 256;   // merged (m,r) over 5120
    const int b  = m0 >> 9;
    floatx4 acc[8][4];
    #pragma unroll
    for (int i = 0; i < 8; ++i)
        #pragma unroll
        for (int j = 0; j < 4; ++j)
            acc[i][j] = (floatx4){0.f, 0.f, 0.f, 0.f};

    const unsigned short* Ab = hp + (size_t)m0 * Hdim;
    const unsigned short* Bb = T + (size_t)b * Ldim * (Rdim * Hdim) + (size_t)n0 * Hdim;
    gemm_bt_core256_cnt(Ab, Hdim, Bb, Hdim, lA, lB, acc);

    const int tid = threadIdx.x, lane = tid & 63, wave = tid >> 6;
    const int wr = wave >> 2, wc = wave & 3;
    const int cl = lane & 15, rh = (lane >> 4) * 4;
    #pragma unroll
    for (int mi = 0; mi < 8; ++mi)
        #pragma unroll
        for (int ni = 0; ni < 4; ++ni) {
            int n = n0 + wc * 64 + ni * 16 + cl;
            float bias = bbil[n % Rdim];
            #pragma unroll
            for (int j = 0; j < 4; ++j) {
                int grow = m0 + wr * 128 + mi * 16 + rh + j;
                rel[(size_t)grow * (Ldim * Rdim) + n] = acc[mi][ni][j] + bias;
            }
        }
}

// ---------------- ent_logits: wave-per-row, 10 dots of length 768 ----------
__global__ __launch_bounds__(256) void k_ent(
    const unsigned short* __restrict__ hp,
    const unsigned short* __restrict__ We,
    const float* __restrict__ bent,
    float* __restrict__ out)
{
    const int gw = (blockIdx.x * blockDim.x + threadIdx.x) >> 6;  // wave id
    const int lane = threadIdx.x & 63;
    if (gw >= Bdim * Ldim) return;
    const unsigned short* row = hp + (size_t)gw * Hdim;
    float hv[12];
    #pragma unroll
    for (int j = 0; j < 12; ++j) hv[j] = bf2f(row[lane + j * 64]);
    #pragma unroll
    for (int e = 0; e < Edim; ++e) {
        const unsigned short* wrow = We + e * Hdim;
        float s = 0.f;
        #pragma unroll
        for (int j = 0; j < 12; ++j) s += hv[j] * bf2f(wrow[lane + j * 64]);
        #pragma unroll
        for (int off = 32; off >= 1; off >>= 1) s += __shfl_xor(s, off);
        if (lane == 0) out[(size_t)gw * Edim + e] = s + bent[e];
    }
}

extern "C" void kernel_launch(void* const* d_in, const int* in_sizes, int n_in,
                              void* d_out, int out_size, void* d_ws, size_t ws_size,
                              hipStream_t stream)
{
    const float* h     = (const float*)d_in[0];
    const float* Wproj = (const float*)d_in[1];
    const float* bproj = (const float*)d_in[2];
    const float* Went  = (const float*)d_in[3];
    const float* bent  = (const float*)d_in[4];
    const float* Wbil  = (const float*)d_in[5];
    const float* bbil  = (const float*)d_in[6];

    float* out_ent = (float*)d_out;
    float* out_rel = (float*)d_out + (size_t)Bdim * Ldim * Edim;

    unsigned short* h_bf  = (unsigned short*)d_ws;
    unsigned short* Wp_bf = h_bf  + (size_t)2048 * Hdim;
    unsigned short* Wb_bf = Wp_bf + (size_t)Hdim * Hdim;
    unsigned short* We_bf = Wb_bf + (size_t)Rdim * Hdim * Hdim;
    unsigned short* hp_bf = We_bf + (size_t)Edim * Hdim;
    unsigned short* T_bf  = hp_bf + (size_t)2048 * Hdim;   // 2048 x 7680

    // single fused conversion launch
    {
        int n0 = 2048 * Hdim / 4;
        int n1 = Hdim * Hdim / 4;
        int n2 = Rdim * Hdim * Hdim / 4;
        int n3 = Edim * Hdim / 4;
        k_cvt4<<<dim3(2048), 256, 0, stream>>>(h, h_bf, n0, Wproj, Wp_bf, n1,
                                               Wbil, Wb_bf, n2, Went, We_bf, n3);
    }

    // GEMM1: hp = relu(h @ Wproj^T + b)   (2048x768) * (768x768), 128^2 tiles
    k_gemm_proj<<<dim3(2048 / 128, Hdim / 128), 256, 0, stream>>>(h_bf, Wp_bf, bproj, hp_bf);

    // ent logits (needs hp)
    k_ent<<<dim3((Bdim * Ldim * 64) / 256), 256, 0, stream>>>(hp_bf, We_bf, bent, out_ent);

    // GEMM2: T = hp @ Wbil^T   (2048x768)*(768x7680), 256^2 tiles, 240 blocks
    k_gemm_t<<<dim3(2048 / 256, (Rdim * Hdim) / 256), 512, 0, stream>>>(hp_bf, Wb_bf, T_bf);

    // GEMM3: rel  (2048 x 5120 x 768, per-256-row-tile B), 160 blocks
    k_gemm_rel<<<dim3(2048 / 256, (Ldim * Rdim) / 256), 512, 0, stream>>>(hp_bf, T_bf, bbil, out_rel);
}

// Round 8
// 169.401 us; speedup vs baseline: 1.1127x; 1.0298x over previous
//
#include <hip/hip_runtime.h>
#include <stdint.h>

#define Bdim 4
#define Ldim 512
#define Hdim 768
#define Edim 10
#define Rdim 10

typedef __attribute__((ext_vector_type(8))) short short8;
typedef __attribute__((ext_vector_type(4))) float floatx4;

__device__ __forceinline__ unsigned short f2bf(float x) {
    unsigned int u = __float_as_uint(x);
    unsigned int r = (u + 0x7fffu + ((u >> 16) & 1u)) >> 16;
    return (unsigned short)r;
}
__device__ __forceinline__ float bf2f(unsigned short u) {
    return __uint_as_float(((unsigned int)u) << 16);
}

#define GLOAD_LDS16(g, l)                                                      \
    __builtin_amdgcn_global_load_lds(                                          \
        (const __attribute__((address_space(1))) void*)(g),                    \
        (__attribute__((address_space(3))) void*)(l), 16, 0, 0)

#define WAITVM(n) asm volatile("s_waitcnt vmcnt(" #n ")" ::: "memory")

// bijective XCD remap of a linear block id (all our grids are %8==0)
__device__ __forceinline__ int xcd_swz(int bid, int nwg) {
    int cpx = nwg >> 3;
    return (bid & 7) * cpx + (bid >> 3);
}

// ====== 256^2 core, BK=64, dbuf, counted vmcnt (R7 — best known) ============
__device__ __forceinline__ void gemm_bt_core256_cnt(
    const unsigned short* __restrict__ A, int lda,
    const unsigned short* __restrict__ Bm, int ldb,
    unsigned short* lA, unsigned short* lB,
    floatx4 acc[8][4])
{
    const int tid  = threadIdx.x;       // 0..511
    const int lane = tid & 63;
    const int wave = tid >> 6;          // 0..7
    const int wr = wave >> 2;           // 0..1  (M)
    const int wc = wave & 3;            // 0..3  (N)

    const int srow   = tid >> 3;                  // 0..63
    const int schunk = (tid & 7) ^ (srow & 7);    // pre-swizzled k-chunk
    const int skk    = schunk << 3;

    const int frow = lane & 15;
    const int fs   = lane >> 4;                   // 0..3

    #define STAGE256(t, buf)                                                   \
        do {                                                                   \
            const int k0s = (t) << 6;                                          \
            unsigned short* dA = lA + (buf) * 16384;                           \
            unsigned short* dB = lB + (buf) * 16384;                           \
            _Pragma("unroll")                                                  \
            for (int i = 0; i < 4; ++i) {                                      \
                GLOAD_LDS16(A  + (size_t)(srow + 64 * i) * lda + k0s + skk,    \
                            dA + (tid + 512 * i) * 8);                         \
                GLOAD_LDS16(Bm + (size_t)(srow + 64 * i) * ldb + k0s + skk,    \
                            dB + (tid + 512 * i) * 8);                         \
            }                                                                  \
        } while (0)

    #define COMPUTE256(buf)                                                    \
        do {                                                                   \
            const unsigned short* sA = lA + (buf) * 16384;                     \
            const unsigned short* sB = lB + (buf) * 16384;                     \
            _Pragma("unroll")                                                  \
            for (int h = 0; h < 2; ++h) {                                      \
                short8 bfr[4];                                                 \
                _Pragma("unroll")                                              \
                for (int ni = 0; ni < 4; ++ni) {                               \
                    int row  = wc * 64 + ni * 16 + frow;                       \
                    int slot = (fs + 4 * h) ^ (row & 7);                       \
                    bfr[ni] = *reinterpret_cast<const short8*>(                \
                        sB + row * 64 + slot * 8);                             \
                }                                                              \
                _Pragma("unroll")                                              \
                for (int mi = 0; mi < 8; ++mi) {                               \
                    int row  = wr * 128 + mi * 16 + frow;                      \
                    int slot = (fs + 4 * h) ^ (row & 7);                       \
                    short8 af = *reinterpret_cast<const short8*>(              \
                        sA + row * 64 + slot * 8);                             \
                    _Pragma("unroll")                                          \
                    for (int ni = 0; ni < 4; ++ni)                             \
                        acc[mi][ni] = __builtin_amdgcn_mfma_f32_16x16x32_bf16( \
                            af, bfr[ni], acc[mi][ni], 0, 0, 0);                \
                }                                                              \
            }                                                                  \
        } while (0)

    const int NT = Hdim >> 6;   // 12

    STAGE256(0, 0);
    for (int kt = 0; kt < NT - 1; ++kt) {
        __builtin_amdgcn_s_barrier();          // readers of tile kt-1 done
        STAGE256(kt + 1, (kt + 1) & 1);        // overwrite tile kt-1's buffer
        WAITVM(8);                             // tile kt landed; kt+1 in flight
        __builtin_amdgcn_s_barrier();          // all waves have tile kt
        __builtin_amdgcn_sched_barrier(0);     // keep ds_reads below barrier
        COMPUTE256(kt & 1);
    }
    __builtin_amdgcn_s_barrier();
    WAITVM(0);                                 // final tile: drain is fine
    __builtin_amdgcn_s_barrier();
    __builtin_amdgcn_sched_barrier(0);
    COMPUTE256((NT - 1) & 1);

    #undef STAGE256
    #undef COMPUTE256
}

// ================= k_prep: proj (f32-direct) + cvt(Wbil,We), fused ==========
// blocks 0..95:  proj 128^2 tile, BK=64, single-buffer 32KB LDS (5 blocks/CU),
//                reg-staged f32 loads -> bf16 cvt -> swizzled ds_write.
// blocks 96.. :  grid-stride f32->bf16 cvt of Wbil then We.
__global__ __launch_bounds__(256) void k_prep(
    const float* __restrict__ h,   const float* __restrict__ Wp,
    const float* __restrict__ bproj,
    const float* __restrict__ Wbil, const float* __restrict__ We,
    unsigned short* __restrict__ hp,
    unsigned short* __restrict__ Wb_bf, unsigned short* __restrict__ We_bf)
{
    __shared__ unsigned short lA[128 * 64];
    __shared__ unsigned short lB[128 * 64];
    const int tid = threadIdx.x;

    if (blockIdx.x >= 96) {
        // ---- cvt part: Wbil (R*H*H) then We (E*H), float4 granularity ----
        const int n2 = Rdim * Hdim * Hdim / 4;
        const int n3 = Edim * Hdim / 4;
        int i = (blockIdx.x - 96) * 256 + tid;
        const int stride = (gridDim.x - 96) * 256;
        for (; i < n2 + n3; i += stride) {
            const float* s; unsigned short* d; int j = i;
            if (j < n2) { s = Wbil; d = Wb_bf; }
            else { j -= n2; s = We; d = We_bf; }
            float4 v = reinterpret_cast<const float4*>(s)[j];
            ushort4 o;
            o.x = f2bf(v.x); o.y = f2bf(v.y); o.z = f2bf(v.z); o.w = f2bf(v.w);
            reinterpret_cast<ushort4*>(d)[j] = o;
        }
        return;
    }

    // ---- proj part ----
    int bid = xcd_swz(blockIdx.x, 96);
    const int m0 = (bid % 16) * 128;
    const int n0 = (bid / 16) * 128;
    const float* Asrc = h  + (size_t)m0 * Hdim;
    const float* Bsrc = Wp + (size_t)n0 * Hdim;

    const int lane = tid & 63;
    const int wave = tid >> 6;
    const int wr = wave >> 1, wc = wave & 1;
    const int frow = lane & 15;
    const int fs   = lane >> 4;

    // staging map: unit q = tid + 256*i covers (row=q>>3, physical chunk=q&7);
    // logical k-chunk lchk = pchk ^ (row&7)  (3-bit XOR swizzle, rule #21:
    // here we control the ds_write so swizzle is applied on the write addr's
    // CONTENT source; read side uses the same XOR).
    floatx4 acc[4][4];
    #pragma unroll
    for (int i = 0; i < 4; ++i)
        #pragma unroll
        for (int j = 0; j < 4; ++j)
            acc[i][j] = (floatx4){0.f, 0.f, 0.f, 0.f};

    float4 ra[4][2], rb[4][2];
    #define LOADREGS(k0s)                                                      \
        _Pragma("unroll")                                                      \
        for (int i = 0; i < 4; ++i) {                                          \
            int q = tid + 256 * i, row = q >> 3, pchk = q & 7;                 \
            int lchk = pchk ^ (row & 7);                                       \
            const float* sa = Asrc + (size_t)row * Hdim + (k0s) + lchk * 8;    \
            const float* sb = Bsrc + (size_t)row * Hdim + (k0s) + lchk * 8;    \
            ra[i][0] = *reinterpret_cast<const float4*>(sa);                   \
            ra[i][1] = *reinterpret_cast<const float4*>(sa + 4);               \
            rb[i][0] = *reinterpret_cast<const float4*>(sb);                   \
            rb[i][1] = *reinterpret_cast<const float4*>(sb + 4);               \
        }

    LOADREGS(0);
    const int NT = Hdim >> 6;    // 12
    for (int kt = 0; kt < NT; ++kt) {
        // convert current regs to packed bf16
        short8 pa[4], pb[4];
        #pragma unroll
        for (int i = 0; i < 4; ++i) {
            pa[i][0] = f2bf(ra[i][0].x); pa[i][1] = f2bf(ra[i][0].y);
            pa[i][2] = f2bf(ra[i][0].z); pa[i][3] = f2bf(ra[i][0].w);
            pa[i][4] = f2bf(ra[i][1].x); pa[i][5] = f2bf(ra[i][1].y);
            pa[i][6] = f2bf(ra[i][1].z); pa[i][7] = f2bf(ra[i][1].w);
            pb[i][0] = f2bf(rb[i][0].x); pb[i][1] = f2bf(rb[i][0].y);
            pb[i][2] = f2bf(rb[i][0].z); pb[i][3] = f2bf(rb[i][0].w);
            pb[i][4] = f2bf(rb[i][1].x); pb[i][5] = f2bf(rb[i][1].y);
            pb[i][6] = f2bf(rb[i][1].z); pb[i][7] = f2bf(rb[i][1].w);
        }
        __syncthreads();   // readers of previous tile done
        #pragma unroll
        for (int i = 0; i < 4; ++i) {
            int q = tid + 256 * i, row = q >> 3, pchk = q & 7;
            *reinterpret_cast<short8*>(lA + row * 64 + pchk * 8) = pa[i];
            *reinterpret_cast<short8*>(lB + row * 64 + pchk * 8) = pb[i];
        }
        if (kt + 1 < NT) LOADREGS((kt + 1) << 6);   // fly under compute
        __syncthreads();   // tile visible
        #pragma unroll
        for (int hh = 0; hh < 2; ++hh) {
            short8 af[4], bfr[4];
            #pragma unroll
            for (int mi = 0; mi < 4; ++mi) {
                int row  = wr * 64 + mi * 16 + frow;
                int slot = (fs + 4 * hh) ^ (row & 7);
                af[mi] = *reinterpret_cast<const short8*>(lA + row * 64 + slot * 8);
            }
            #pragma unroll
            for (int ni = 0; ni < 4; ++ni) {
                int row  = wc * 64 + ni * 16 + frow;
                int slot = (fs + 4 * hh) ^ (row & 7);
                bfr[ni] = *reinterpret_cast<const short8*>(lB + row * 64 + slot * 8);
            }
            #pragma unroll
            for (int mi = 0; mi < 4; ++mi)
                #pragma unroll
                for (int ni = 0; ni < 4; ++ni)
                    acc[mi][ni] = __builtin_amdgcn_mfma_f32_16x16x32_bf16(
                        af[mi], bfr[ni], acc[mi][ni], 0, 0, 0);
        }
    }
    #undef LOADREGS

    const int cl = lane & 15, rh = (lane >> 4) * 4;
    #pragma unroll
    for (int mi = 0; mi < 4; ++mi)
        #pragma unroll
        for (int ni = 0; ni < 4; ++ni)
            #pragma unroll
            for (int j = 0; j < 4; ++j) {
                int r = m0 + wr * 64 + mi * 16 + rh + j;
                int c = n0 + wc * 64 + ni * 16 + cl;
                float v = acc[mi][ni][j] + bproj[c];
                hp[(size_t)r * Hdim + c] = f2bf(fmaxf(v, 0.0f));
            }
}

// -------- GEMM2 (256^2 cnt): T[m, r*768+h] = hp @ Wbil^T -> bf16 -----------
__global__ __launch_bounds__(512, 1) void k_gemm_t(
    const unsigned short* __restrict__ hp,
    const unsigned short* __restrict__ Wb,
    unsigned short* __restrict__ T)
{
    __shared__ unsigned short lA[2 * 256 * 64];
    __shared__ unsigned short lB[2 * 256 * 64];
    int bid = xcd_swz(blockIdx.x + gridDim.x * blockIdx.y, gridDim.x * gridDim.y);
    const int m0 = (bid % gridDim.x) * 256;
    const int n0 = (bid / gridDim.x) * 256;   // over R*H = 7680
    floatx4 acc[8][4];
    #pragma unroll
    for (int i = 0; i < 8; ++i)
        #pragma unroll
        for (int j = 0; j < 4; ++j)
            acc[i][j] = (floatx4){0.f, 0.f, 0.f, 0.f};

    gemm_bt_core256_cnt(hp + (size_t)m0 * Hdim, Hdim,
                        Wb + (size_t)n0 * Hdim, Hdim, lA, lB, acc);

    const int tid = threadIdx.x, lane = tid & 63, wave = tid >> 6;
    const int wr = wave >> 2, wc = wave & 3;
    const int cl = lane & 15, rh = (lane >> 4) * 4;
    #pragma unroll
    for (int mi = 0; mi < 8; ++mi)
        #pragma unroll
        for (int ni = 0; ni < 4; ++ni)
            #pragma unroll
            for (int j = 0; j < 4; ++j) {
                int r = m0 + wr * 128 + mi * 16 + rh + j;
                int c = n0 + wc * 64 + ni * 16 + cl;
                T[(size_t)r * (Rdim * Hdim) + c] = f2bf(acc[mi][ni][j]);
            }
}

// ---- k_rel_ent: rel GEMM (blocks 0..159) + ent_logits (blocks 160..191) ----
__global__ __launch_bounds__(512, 1) void k_rel_ent(
    const unsigned short* __restrict__ hp,
    const unsigned short* __restrict__ T,
    const float* __restrict__ bbil,
    float* __restrict__ rel,
    const unsigned short* __restrict__ We,
    const float* __restrict__ bent,
    float* __restrict__ out_ent)
{
    __shared__ unsigned short lA[2 * 256 * 64];
    __shared__ unsigned short lB[2 * 256 * 64];
    const int tid = threadIdx.x, lane = tid & 63, wave = tid >> 6;

    if (blockIdx.x >= 160) {
        // ---- ent: 32 blocks x 8 waves x 8 rows = 2048 rows ----
        const int e = blockIdx.x - 160;
        const int base = (e * 8 + wave) * 8;
        for (int rr = 0; rr < 8; ++rr) {
            const unsigned short* row = hp + (size_t)(base + rr) * Hdim;
            float hv[12];
            #pragma unroll
            for (int j = 0; j < 12; ++j) hv[j] = bf2f(row[lane + j * 64]);
            #pragma unroll
            for (int ee = 0; ee < Edim; ++ee) {
                const unsigned short* wrow = We + ee * Hdim;
                float s = 0.f;
                #pragma unroll
                for (int j = 0; j < 12; ++j) s += hv[j] * bf2f(wrow[lane + j * 64]);
                #pragma unroll
                for (int off = 32; off >= 1; off >>= 1) s += __shfl_xor(s, off);
                if (lane == 0) out_ent[(size_t)(base + rr) * Edim + ee] = s + bent[ee];
            }
        }
        return;
    }

    // ---- rel GEMM (N-merged): rel[grow, m*10+r] = hp @ T2_b^T + bbil[r] ----
    int bid = xcd_swz(blockIdx.x, 160);
    const int m0 = (bid & 7) * 256;           // global row over 2048 (8 tiles)
    const int n0 = (bid >> 3) * 256;          // merged (m,r) over 5120 (20)
    const int b  = m0 >> 9;
    floatx4 acc[8][4];
    #pragma unroll
    for (int i = 0; i < 8; ++i)
        #pragma unroll
        for (int j = 0; j < 4; ++j)
            acc[i][j] = (floatx4){0.f, 0.f, 0.f, 0.f};

    const unsigned short* Ab = hp + (size_t)m0 * Hdim;
    const unsigned short* Bb = T + (size_t)b * Ldim * (Rdim * Hdim) + (size_t)n0 * Hdim;
    gemm_bt_core256_cnt(Ab, Hdim, Bb, Hdim, lA, lB, acc);

    const int wr = wave >> 2, wc = wave & 3;
    const int cl = lane & 15, rh = (lane >> 4) * 4;
    #pragma unroll
    for (int mi = 0; mi < 8; ++mi)
        #pragma unroll
        for (int ni = 0; ni < 4; ++ni) {
            int n = n0 + wc * 64 + ni * 16 + cl;
            float bias = bbil[n % Rdim];
            #pragma unroll
            for (int j = 0; j < 4; ++j) {
                int grow = m0 + wr * 128 + mi * 16 + rh + j;
                rel[(size_t)grow * (Ldim * Rdim) + n] = acc[mi][ni][j] + bias;
            }
        }
}

extern "C" void kernel_launch(void* const* d_in, const int* in_sizes, int n_in,
                              void* d_out, int out_size, void* d_ws, size_t ws_size,
                              hipStream_t stream)
{
    const float* h     = (const float*)d_in[0];
    const float* Wproj = (const float*)d_in[1];
    const float* bproj = (const float*)d_in[2];
    const float* Went  = (const float*)d_in[3];
    const float* bent  = (const float*)d_in[4];
    const float* Wbil  = (const float*)d_in[5];
    const float* bbil  = (const float*)d_in[6];

    float* out_ent = (float*)d_out;
    float* out_rel = (float*)d_out + (size_t)Bdim * Ldim * Edim;

    unsigned short* Wb_bf = (unsigned short*)d_ws;
    unsigned short* We_bf = Wb_bf + (size_t)Rdim * Hdim * Hdim;
    unsigned short* hp_bf = We_bf + (size_t)Edim * Hdim;
    unsigned short* T_bf  = hp_bf + (size_t)2048 * Hdim;   // 2048 x 7680

    // 1) fused: proj (f32-direct, blocks 0..95) + cvt Wbil/We (blocks 96..1119)
    k_prep<<<dim3(1120), 256, 0, stream>>>(h, Wproj, bproj, Wbil, Went,
                                           hp_bf, Wb_bf, We_bf);

    // 2) GEMM2: T = hp @ Wbil^T  (2048x768)*(768x7680), 256^2, 240 blocks
    k_gemm_t<<<dim3(2048 / 256, (Rdim * Hdim) / 256), 512, 0, stream>>>(hp_bf, Wb_bf, T_bf);

    // 3) rel GEMM (160 blocks) + ent (32 blocks) in one launch
    k_rel_ent<<<dim3(192), 512, 0, stream>>>(hp_bf, T_bf, bbil, out_rel,
                                             We_bf, bent, out_ent);
}